// Round 4
// baseline (171.383 us; speedup 1.0000x reference)
//
#include <hip/hip_runtime.h>

// ALayer: out = conv3x3(x, weight*A_w) * sigmoid(conv3x3(relu(conv3x3(x,se_w1)), se_w2))
// B=8, C=256, H=W=56. bf16 MFMA implicit GEMM on NHWC-padded input.
// Round 4: 3 dispatches total. k_main: slab-resident B (stage once per cc, all 9
// taps read shifted), A double-buffered w/ counted vmcnt(4), XCD swizzle (1 batch
// per XCD), fused SE2+sigmoid epilogue. k_pre fuses transform+prep+border zeroing.

typedef unsigned short u16;
typedef __bf16 bf16x8 __attribute__((ext_vector_type(8)));
typedef unsigned short us8 __attribute__((ext_vector_type(8)));
typedef unsigned short us4v __attribute__((ext_vector_type(4)));
typedef float f32x4 __attribute__((ext_vector_type(4)));
typedef float f4v __attribute__((ext_vector_type(4)));

#define HP 58   // padded H/W
#define HW 3136 // 56*56

__device__ __forceinline__ u16 f2bf(float f) {
  unsigned u = __float_as_uint(f);
  u = (u + 0x7fffu + ((u >> 16) & 1u)) >> 16;  // RNE, inputs finite
  return (u16)u;
}
__device__ __forceinline__ float bf2f(u16 v) {
  return __uint_as_float(((unsigned)v) << 16);
}

// async global->LDS, 16B per lane. LDS dest is wave-uniform base + lane*16.
__device__ __forceinline__ void gload16(const u16* g, u16* l) {
  __builtin_amdgcn_global_load_lds((const __attribute__((address_space(1))) void*)g,
                                   (__attribute__((address_space(3))) void*)l,
                                   16, 0, 0);
}

// ---------- k_pre: fused transform (NCHW f32 -> padded NHWC bf16) + weight prep
// + border zeroing (replaces 2 memsets + k_prep + k_transform).
// blocks [0,448): transform row (h = bid%56, b = bid/56) + zero cols 0,57 of that row
// blocks [448,2896): prep wb/w1b
// blocks [2896,3072): zero xp rows 0,57 (all b) + all of se1p
__global__ __launch_bounds__(256) void k_pre(const float* __restrict__ x,
                                             const float* __restrict__ weight,
                                             const float* __restrict__ A_w,
                                             const float* __restrict__ se_w1,
                                             u16* __restrict__ xp, u16* __restrict__ wb,
                                             u16* __restrict__ w1b, u16* __restrict__ se1p) {
  __shared__ __align__(16) u16 trans[56 * 72];
  const int bid = blockIdx.x;
  const int t = threadIdx.x;
  if (bid < 448) {
    const int h = bid % 56, b = bid / 56;
    // zero border cols 0 and 57 of padded row h+1
    if (t < 64) {
      int half = t >> 5, seg = t & 31;
      us8 z8 = {};
      *(us8*)(xp + ((size_t)((b * HP + h + 1) * HP + half * 57)) * 256 + seg * 8) = z8;
    }
    for (int cc = 0; cc < 4; ++cc) {
      const int c0 = cc * 64;
#pragma unroll
      for (int i = 0; i < 4; ++i) {
        int idx = t + 256 * i;
        if (idx < 896) {
          int ci = idx / 14, s = idx % 14;
          f4v v = *(const f4v*)(x + ((size_t)(b * 256 + c0 + ci)) * HW + h * 56 + s * 4);
#pragma unroll
          for (int j = 0; j < 4; ++j) trans[(s * 4 + j) * 72 + ci] = f2bf(v[j]);
        }
      }
      __syncthreads();
#pragma unroll
      for (int i = 0; i < 2; ++i) {
        int idx = t + 256 * i;
        if (idx < 448) {
          int w = idx >> 3, seg = idx & 7;
          us8 v = *(const us8*)&trans[w * 72 + seg * 8];
          *(us8*)(xp + ((size_t)((b * HP + h + 1) * HP + (w + 1))) * 256 + c0 + seg * 8) = v;
        }
      }
      __syncthreads();
    }
  } else if (bid < 2896) {
    int idx = (bid - 448) * 256 + t;
    if (idx < 589824) {
      int tap = idx >> 16; int rem = idx & 65535; int o = rem >> 8; int c = rem & 255;
      wb[idx] = f2bf(weight[(o * 256 + c) * 9 + tap] * A_w[c * 9 + tap]);
    } else if (idx < 589824 + 36864) {
      int j = idx - 589824;
      int tap = j >> 12; int rem = j & 4095; int o = rem >> 8; int c = rem & 255;
      w1b[j] = f2bf(se_w1[(o * 256 + c) * 9 + tap]);
    }
  } else {
    int zid = (bid - 2896) * 256 + t;  // 0..45055
    us8 z8 = {};
#pragma unroll
    for (int j = 0; j < 2; ++j) {
      int ch = zid + j * 45056;
      if (ch < 29696) {  // xp rows 0 and 57, all b: 8 * 3712 chunks
        int b = ch / 3712; int rem = ch - b * 3712;
        int row = (rem < 1856) ? 0 : 57;
        int r2 = (rem < 1856) ? rem : rem - 1856;
        int col = r2 >> 5, seg = r2 & 31;
        *(us8*)(xp + ((size_t)((b * HP + row) * HP + col)) * 256 + seg * 8) = z8;
      } else if (ch < 29696 + 53824) {  // all of se1p
        int c2 = ch - 29696;
        *(us8*)(se1p + (size_t)c2 * 8) = z8;
      }
    }
  }
}

// ---------- SE conv1 + relu: M=16, N=128 (2 rows x 64), full K per block.
// Input slab staged once per cc and reused across all 9 taps. 1-D swizzled grid (224).
__global__ __launch_bounds__(256) void k_se1(const u16* __restrict__ xp,
                                             const u16* __restrict__ w1b,
                                             u16* __restrict__ se1p) {
  __shared__ __align__(16) u16 Alds[144 * 8 * 8];       // 18432 B, swizzled [row][seg]
  __shared__ __align__(16) u16 slab[2080 * 8];          // 33280 B
  const int t = threadIdx.x;
  const int lane = t & 63;
  const int wv = t >> 6;
  const int l15 = lane & 15, lg = lane >> 4;
  const int wg = blockIdx.x;      // 224 = 28 per XCD
  const int b = wg & 7;           // one batch per XCD
  const int h0 = (wg >> 3) * 2;

  f32x4 acc[2];
  f32x4 z = {0.f, 0.f, 0.f, 0.f};
  acc[0] = z; acc[1] = z;

  for (int cc = 0; cc < 4; ++cc) {
    const int c0 = cc * 64;
    __syncthreads();
    for (int idx = t; idx < 1152; idx += 256) {
      int row = idx >> 3, seg = idx & 7;
      us8 v = *(const us8*)(w1b + ((size_t)row * 256 + c0 + seg * 8));
      *(us8*)&Alds[(row * 8 + (seg ^ (row & 7))) * 8] = v;
    }
#pragma unroll
    for (int i = 0; i < 8; ++i) {
      int s_lin = wv * 512 + i * 64 + lane;
      int r = s_lin >> 9, col = (s_lin >> 3) & 63, seg = s_lin & 7;
      const u16* src = xp + ((size_t)((b * HP + h0 + r) * HP + col)) * 256 + c0 +
                       ((seg ^ (col & 7)) * 8);
      gload16(src, &slab[(wv * 512 + i * 64) * 8]);
    }
    __syncthreads();
    for (int dh = 0; dh < 3; ++dh) {
      for (int dw = 0; dw < 3; ++dw) {
        const int tap = dh * 3 + dw;
#pragma unroll
        for (int kk = 0; kk < 2; ++kk) {
          int arow = tap * 16 + l15;
          bf16x8 af = *(const bf16x8*)&Alds[(arow * 8 + ((kk * 4 + lg) ^ (arow & 7))) * 8];
#pragma unroll
          for (int nt = 0; nt < 2; ++nt) {
            int p = wv * 32 + nt * 16 + l15;
            int rr = (p >> 6) + dh, col = (p & 63) + dw;
            bf16x8 bfr = *(const bf16x8*)&slab[((rr * 64 + col) * 8 + ((kk * 4 + lg) ^ (col & 7))) * 8];
            acc[nt] = __builtin_amdgcn_mfma_f32_16x16x32_bf16(af, bfr, acc[nt], 0, 0, 0);
          }
        }
      }
    }
  }
#pragma unroll
  for (int nt = 0; nt < 2; ++nt) {
    int p = wv * 32 + nt * 16 + l15;
    int r = p >> 6, w = p & 63;
    if (w < 56) {
      us4v pk;
#pragma unroll
      for (int reg = 0; reg < 4; ++reg) {
        float v = acc[nt][reg];
        v = v > 0.f ? v : 0.f;
        pk[reg] = f2bf(v);
      }
      *(us4v*)(se1p + ((size_t)((b * HP + h0 + r + 1) * HP + (w + 1))) * 16 + lg * 4) = pk;
    }
  }
}

// ---------- main conv: BM=128, BN=128 (2 rows x 64), 4 waves (2x2).
// B slab [4 rows][64 cols][64 ch] resident per cc (staged once, 9 taps read shifted);
// A double-buffered with counted vmcnt(4). Fused SE2+sigmoid epilogue.
__global__ __launch_bounds__(256) void k_main(const u16* __restrict__ xp,
                                              const u16* __restrict__ wb,
                                              const u16* __restrict__ se1p,
                                              const float* __restrict__ se_w2,
                                              float* __restrict__ out) {
  __shared__ __align__(16) u16 slab[4 * 64 * 8 * 8];   // 32768 B
  __shared__ __align__(16) u16 Albuf[2][128 * 64];     // 2 x 16384 B
  __shared__ float w2s[144];
  __shared__ float amap_s[128];
  const int t = threadIdx.x;
  const int lane = t & 63;
  const int wid = t >> 6;
  const int wm = wid >> 1;          // 0..1 : 64 out-channels
  const int wn = wid & 1;           // 0..1 : 64 pixels
  const int l15 = lane & 15, lg = lane >> 4;
  const int lrow = lane >> 3, lseg = lane & 7;
  // XCD swizzle: 448 blocks, 56 per XCD -> each XCD owns one batch b
  const int wg = blockIdx.x;
  const int b = wg & 7;
  const int rem = wg >> 3;          // 0..55
  const int h0 = (rem >> 1) * 2;
  const int mbase = (rem & 1) * 128;

  if (t < 144) w2s[t] = se_w2[t];

  f32x4 acc[4][4];
  f32x4 z = {0.f, 0.f, 0.f, 0.f};
#pragma unroll
  for (int mt = 0; mt < 4; ++mt)
#pragma unroll
    for (int nt = 0; nt < 4; ++nt) acc[mt][nt] = z;

  auto stage_slab = [&](int cc) {
    const int c0 = cc * 64;
#pragma unroll
    for (int i = 0; i < 8; ++i) {
      int chunk = wid * 512 + i * 64 + lane;
      int row = chunk >> 9, col = (chunk >> 3) & 63, seg = chunk & 7;
      const u16* src = xp + ((size_t)((b * HP + h0 + row) * HP + col)) * 256 + c0 +
                       ((seg ^ (col & 7)) * 8);
      gload16(src, &slab[(wid * 512 + i * 64) * 8]);
    }
  };
  auto stage_A = [&](int tap, int cc, int buf) {
    const int c0 = cc * 64;
#pragma unroll
    for (int i = 0; i < 4; ++i) {
      int li = wid * 4 + i;
      int row = li * 8 + lrow;
      const u16* src = wb + ((size_t)(tap * 256 + mbase + row)) * 256 + c0 +
                       ((lseg ^ (row & 7)) * 8);
      gload16(src, &Albuf[buf][li * 512]);
    }
  };

  stage_slab(0);
  stage_A(0, 0, 0);
  int pb = 0;
  for (int cc = 0; cc < 4; ++cc) {
    for (int tap = 0; tap < 9; ++tap) {
      if (tap < 8) {
        stage_A(tap + 1, cc, pb ^ 1);
        asm volatile("s_waitcnt vmcnt(4)" ::: "memory");
      } else {
        asm volatile("s_waitcnt vmcnt(0)" ::: "memory");
      }
      __builtin_amdgcn_s_barrier();
      __builtin_amdgcn_sched_barrier(0);
      const int dh = tap / 3, dw = tap % 3;
#pragma unroll
      for (int kk = 0; kk < 2; ++kk) {
        bf16x8 af[4], bfr[4];
#pragma unroll
        for (int mt = 0; mt < 4; ++mt) {
          int row = wm * 64 + mt * 16 + l15;
          af[mt] = *(const bf16x8*)&Albuf[pb][row * 64 + (((kk * 4 + lg) ^ (row & 7)) * 8)];
        }
#pragma unroll
        for (int nt = 0; nt < 4; ++nt) {
          int p = wn * 64 + nt * 16 + l15;
          int r = (p >> 6) + dh;
          int col = ((p & 63) + dw) & 63;
          bfr[nt] = *(const bf16x8*)&slab[((r * 64 + col) * 8 + ((kk * 4 + lg) ^ (col & 7))) * 8];
        }
#pragma unroll
        for (int mt = 0; mt < 4; ++mt)
#pragma unroll
          for (int nt = 0; nt < 4; ++nt)
            acc[mt][nt] = __builtin_amdgcn_mfma_f32_16x16x32_bf16(af[mt], bfr[nt], acc[mt][nt], 0, 0, 0);
      }
      __builtin_amdgcn_sched_barrier(0);
      __builtin_amdgcn_s_barrier();
      if (tap < 8) {
        pb ^= 1;
      } else if (cc < 3) {
        stage_slab(cc + 1);
        stage_A(0, cc + 1, pb);  // folded into next phase's vmcnt(4)
      }
    }
  }
  // fused SE2 + sigmoid: 112 pixels per block
  if (t < 112) {
    int r = t / 56, w = t - r * 56;
    int h = h0 + r;
    float s = 0.f;
    for (int dh2 = 0; dh2 < 3; ++dh2) {
#pragma unroll
      for (int dw2 = 0; dw2 < 3; ++dw2) {
        const u16* src = se1p + ((size_t)((b * HP + h + dh2) * HP + (w + dw2))) * 16;
        us8 v0 = *(const us8*)src;
        us8 v1 = *(const us8*)(src + 8);
        int tap = dh2 * 3 + dw2;
#pragma unroll
        for (int ci = 0; ci < 8; ++ci) s += bf2f(v0[ci]) * w2s[ci * 9 + tap];
#pragma unroll
        for (int ci = 0; ci < 8; ++ci) s += bf2f(v1[ci]) * w2s[(8 + ci) * 9 + tap];
      }
    }
    amap_s[t] = 1.f / (1.f + expf(-s));
  }
  __syncthreads();
  // epilogue: multiply by attention map, store NCHW fp32
#pragma unroll
  for (int nt = 0; nt < 4; ++nt) {
    int n = wn * 64 + nt * 16 + l15;
    int r = n >> 6, w = n & 63;
    if (w < 56) {
      float av = amap_s[r * 56 + w];
#pragma unroll
      for (int mt = 0; mt < 4; ++mt) {
        int obase = mbase + wm * 64 + mt * 16 + lg * 4;
#pragma unroll
        for (int reg = 0; reg < 4; ++reg) {
          out[((size_t)(b * 256 + obase + reg) * 56 + h0 + r) * 56 + w] = acc[mt][nt][reg] * av;
        }
      }
    }
  }
}

extern "C" void kernel_launch(void* const* d_in, const int* in_sizes, int n_in,
                              void* d_out, int out_size, void* d_ws, size_t ws_size,
                              hipStream_t stream) {
  const float* x      = (const float*)d_in[0];
  const float* weight = (const float*)d_in[1];
  const float* A_w    = (const float*)d_in[2];
  const float* se_w1  = (const float*)d_in[3];
  const float* se_w2  = (const float*)d_in[4];
  float* out = (float*)d_out;

  char* ws = (char*)d_ws;
  // ws layout (bytes):
  // xp   : [8][58][58][256] bf16 = 13,778,944
  // se1p : [8][58][58][16]  bf16 =    861,184
  // wb   : [9][256][256]    bf16 =  1,179,648
  // w1b  : [9][16][256]     bf16 =     73,728
  u16* xp   = (u16*)ws;
  u16* se1p = (u16*)(ws + 13778944);
  u16* wb   = (u16*)(ws + 14640128);
  u16* w1b  = (u16*)(ws + 15819776);

  k_pre<<<dim3(3072), dim3(256), 0, stream>>>(x, weight, A_w, se_w1, xp, wb, w1b, se1p);
  k_se1<<<dim3(224), dim3(256), 0, stream>>>(xp, w1b, se1p);
  k_main<<<dim3(448), dim3(256), 0, stream>>>(xp, wb, se1p, se_w2, out);
}

// Round 5
// 160.280 us; speedup vs baseline: 1.0693x; 1.0693x over previous
//
#include <hip/hip_runtime.h>

// ALayer: out = conv3x3(x, weight*A_w) * sigmoid(conv3x3(relu(conv3x3(x,se_w1)), se_w2))
// B=8, C=256, H=W=56. bf16 MFMA implicit GEMM on NHWC-padded input.
// Round 5: k_main LDS cut to 48KB (3 blocks/CU): slab-resident B + single A buffer
// with reg-staged (global->VGPR->ds_write) double buffering. k_se1 at 448 blocks.
// XCD swizzle kept (FETCH 41.6->13.2GB in round 4). SE2 fused in k_main epilogue
// with LDS overlay.

typedef unsigned short u16;
typedef __bf16 bf16x8 __attribute__((ext_vector_type(8)));
typedef unsigned short us8 __attribute__((ext_vector_type(8)));
typedef unsigned short us4v __attribute__((ext_vector_type(4)));
typedef float f32x4 __attribute__((ext_vector_type(4)));
typedef float f4v __attribute__((ext_vector_type(4)));

#define HP 58   // padded H/W
#define HW 3136 // 56*56

__device__ __forceinline__ u16 f2bf(float f) {
  unsigned u = __float_as_uint(f);
  u = (u + 0x7fffu + ((u >> 16) & 1u)) >> 16;  // RNE, inputs finite
  return (u16)u;
}
__device__ __forceinline__ float bf2f(u16 v) {
  return __uint_as_float(((unsigned)v) << 16);
}

// async global->LDS, 16B per lane. LDS dest is wave-uniform base + lane*16.
__device__ __forceinline__ void gload16(const u16* g, u16* l) {
  __builtin_amdgcn_global_load_lds((const __attribute__((address_space(1))) void*)g,
                                   (__attribute__((address_space(3))) void*)l,
                                   16, 0, 0);
}

// ---------- k_pre: fused transform (NCHW f32 -> padded NHWC bf16) + weight prep
// + border zeroing.
__global__ __launch_bounds__(256) void k_pre(const float* __restrict__ x,
                                             const float* __restrict__ weight,
                                             const float* __restrict__ A_w,
                                             const float* __restrict__ se_w1,
                                             u16* __restrict__ xp, u16* __restrict__ wb,
                                             u16* __restrict__ w1b, u16* __restrict__ se1p) {
  __shared__ __align__(16) u16 trans[56 * 72];
  const int bid = blockIdx.x;
  const int t = threadIdx.x;
  if (bid < 448) {
    const int h = bid % 56, b = bid / 56;
    if (t < 64) {
      int half = t >> 5, seg = t & 31;
      us8 z8 = {};
      *(us8*)(xp + ((size_t)((b * HP + h + 1) * HP + half * 57)) * 256 + seg * 8) = z8;
    }
    for (int cc = 0; cc < 4; ++cc) {
      const int c0 = cc * 64;
#pragma unroll
      for (int i = 0; i < 4; ++i) {
        int idx = t + 256 * i;
        if (idx < 896) {
          int ci = idx / 14, s = idx % 14;
          f4v v = *(const f4v*)(x + ((size_t)(b * 256 + c0 + ci)) * HW + h * 56 + s * 4);
#pragma unroll
          for (int j = 0; j < 4; ++j) trans[(s * 4 + j) * 72 + ci] = f2bf(v[j]);
        }
      }
      __syncthreads();
#pragma unroll
      for (int i = 0; i < 2; ++i) {
        int idx = t + 256 * i;
        if (idx < 448) {
          int w = idx >> 3, seg = idx & 7;
          us8 v = *(const us8*)&trans[w * 72 + seg * 8];
          *(us8*)(xp + ((size_t)((b * HP + h + 1) * HP + (w + 1))) * 256 + c0 + seg * 8) = v;
        }
      }
      __syncthreads();
    }
  } else if (bid < 2896) {
    int idx = (bid - 448) * 256 + t;
    if (idx < 589824) {
      int tap = idx >> 16; int rem = idx & 65535; int o = rem >> 8; int c = rem & 255;
      wb[idx] = f2bf(weight[(o * 256 + c) * 9 + tap] * A_w[c * 9 + tap]);
    } else if (idx < 589824 + 36864) {
      int j = idx - 589824;
      int tap = j >> 12; int rem = j & 4095; int o = rem >> 8; int c = rem & 255;
      w1b[j] = f2bf(se_w1[(o * 256 + c) * 9 + tap]);
    }
  } else {
    int zid = (bid - 2896) * 256 + t;  // 0..45055
    us8 z8 = {};
#pragma unroll
    for (int j = 0; j < 2; ++j) {
      int ch = zid + j * 45056;
      if (ch < 29696) {  // xp rows 0 and 57, all b
        int b = ch / 3712; int rem = ch - b * 3712;
        int row = (rem < 1856) ? 0 : 57;
        int r2 = (rem < 1856) ? rem : rem - 1856;
        int col = r2 >> 5, seg = r2 & 31;
        *(us8*)(xp + ((size_t)((b * HP + row) * HP + col)) * 256 + seg * 8) = z8;
      } else if (ch < 29696 + 53824) {  // all of se1p
        int c2 = ch - 29696;
        *(us8*)(se1p + (size_t)c2 * 8) = z8;
      }
    }
  }
}

// ---------- SE conv1 + relu: one output row per block (448 blocks), M=16, N=64.
// 3-row slab staged once per cc, reused across all 9 taps. LDS 43KB -> 3 blocks/CU.
__global__ __launch_bounds__(256) void k_se1(const u16* __restrict__ xp,
                                             const u16* __restrict__ w1b,
                                             u16* __restrict__ se1p) {
  __shared__ __align__(16) u16 Alds[144 * 64];      // 18432 B, swizzled [row][slot]
  __shared__ __align__(16) u16 slab[3 * 64 * 64];   // 24576 B
  const int t = threadIdx.x;
  const int lane = t & 63;
  const int wv = t >> 6;
  const int l15 = lane & 15, lg = lane >> 4;
  const int wg = blockIdx.x;      // 448: b = XCD
  const int b = wg & 7;
  const int h = wg >> 3;          // output row 0..55

  f32x4 acc = {0.f, 0.f, 0.f, 0.f};

  for (int cc = 0; cc < 4; ++cc) {
    const int c0 = cc * 64;
    __syncthreads();
    // stage A: 9 taps x 16 rows x 8 segs (VALU, small)
    for (int idx = t; idx < 1152; idx += 256) {
      int row = idx >> 3, seg = idx & 7;
      us8 v = *(const us8*)(w1b + ((size_t)row * 256 + c0 + seg * 8));
      *(us8*)&Alds[row * 64 + (seg ^ (row & 7)) * 8] = v;
    }
    // stage slab: 3 rows x 64 cols x 8 segs = 1536 chunks, pre-swizzled source
#pragma unroll
    for (int i = 0; i < 6; ++i) {
      int chunk = i * 256 + t;
      int row = chunk >> 9, col = (chunk >> 3) & 63, seg = chunk & 7;
      const u16* src = xp + ((size_t)((b * HP + h + row) * HP + col)) * 256 + c0 +
                       ((seg ^ (col & 7)) * 8);
      gload16(src, &slab[(i * 256 + wv * 64) * 8]);
    }
    __syncthreads();
#pragma unroll
    for (int tap = 0; tap < 9; ++tap) {
      const int dh = tap / 3, dw = tap % 3;
#pragma unroll
      for (int kk = 0; kk < 2; ++kk) {
        int arow = tap * 16 + l15;
        bf16x8 af = *(const bf16x8*)&Alds[arow * 64 + (((kk * 4 + lg) ^ (arow & 7))) * 8];
        int col = ((wv * 16 + l15) + dw) & 63;
        bf16x8 bfr = *(const bf16x8*)&slab[((dh * 64 + col) * 8 + ((kk * 4 + lg) ^ (col & 7))) * 8];
        acc = __builtin_amdgcn_mfma_f32_16x16x32_bf16(af, bfr, acc, 0, 0, 0);
      }
    }
  }
  int w = wv * 16 + l15;
  if (w < 56) {
    us4v pk;
#pragma unroll
    for (int reg = 0; reg < 4; ++reg) {
      float v = acc[reg];
      v = v > 0.f ? v : 0.f;
      pk[reg] = f2bf(v);
    }
    *(us4v*)(se1p + ((size_t)((b * HP + h + 1) * HP + (w + 1))) * 16 + lg * 4) = pk;
  }
}

// ---------- main conv: BM=128, BN=128 (2 rows x 64), 4 waves (2x2). LDS 48KB.
// B slab resident per cc (9 taps read shifted); A single LDS buffer with
// reg-staged prefetch (global->VGPR before compute, ds_write after barrier).
__global__ __launch_bounds__(256) void k_main(const u16* __restrict__ xp,
                                              const u16* __restrict__ wb,
                                              const u16* __restrict__ se1p,
                                              const float* __restrict__ se_w2,
                                              float* __restrict__ out) {
  __shared__ __align__(16) u16 S[24576];  // 49152 B total
  u16* slab  = S;           // 16384 u16 = 32KB : [4 rows][64 cols][8 slots][8]
  u16* Albuf = S + 16384;   // 8192 u16 = 16KB : [128 rows][8 slots][8]
  float* w2s    = (float*)S;          // epilogue overlay (slab dead by then)
  float* amap_s = (float*)(S + 512);  // byte offset 1024
  const int t = threadIdx.x;
  const int lane = t & 63;
  const int wid = t >> 6;
  const int wm = wid >> 1;          // 0..1 : 64 out-channels
  const int wn = wid & 1;           // 0..1 : 64 pixels
  const int l15 = lane & 15, lg = lane >> 4;
  const int lrow = lane >> 3, lseg = lane & 7;
  // XCD swizzle: 448 blocks, 56 per XCD -> each XCD owns one batch b
  const int wg = blockIdx.x;
  const int b = wg & 7;
  const int rem = wg >> 3;          // 0..55
  const int h0 = (rem >> 1) * 2;
  const int mbase = (rem & 1) * 128;

  f32x4 acc[4][4];
#pragma unroll
  for (int mt = 0; mt < 4; ++mt)
#pragma unroll
    for (int nt = 0; nt < 4; ++nt) {
      f32x4 z = {0.f, 0.f, 0.f, 0.f};
      acc[mt][nt] = z;
    }

  auto stage_slab = [&](int cc) {
    const int c0 = cc * 64;
#pragma unroll
    for (int i = 0; i < 8; ++i) {
      int chunk = wid * 512 + i * 64 + lane;
      int row = chunk >> 9, col = (chunk >> 3) & 63, seg = chunk & 7;
      const u16* src = xp + ((size_t)((b * HP + h0 + row) * HP + col)) * 256 + c0 +
                       ((seg ^ (col & 7)) * 8);
      gload16(src, &slab[(wid * 512 + i * 64) * 8]);
    }
  };
  auto loadA = [&](int tap, int cc, us8* ra) {
    const int c0 = cc * 64;
#pragma unroll
    for (int i = 0; i < 4; ++i) {
      int row = wid * 32 + i * 8 + lrow;
      ra[i] = *(const us8*)(wb + ((size_t)(tap * 256 + mbase + row)) * 256 + c0 + lseg * 8);
    }
  };
  auto writeA = [&](const us8* ra) {
#pragma unroll
    for (int i = 0; i < 4; ++i) {
      int row = wid * 32 + i * 8 + lrow;
      *(us8*)&Albuf[row * 64 + (lseg ^ (row & 7)) * 8] = ra[i];
    }
  };

  {  // prologue: A(0,0) + slab(0)
    us8 ra[4];
    loadA(0, 0, ra);
    stage_slab(0);
    writeA(ra);         // compiler waits the reg loads
    __syncthreads();    // drains slab gloads + ds_writes
  }

  for (int cc = 0; cc < 4; ++cc) {
#pragma unroll
    for (int tap = 0; tap < 9; ++tap) {
      const bool haveNext = !(cc == 3 && tap == 8);
      us8 ra[4];
      if (haveNext) loadA(tap < 8 ? tap + 1 : 0, tap < 8 ? cc : cc + 1, ra);
      const int dh = tap / 3, dw = tap % 3;
#pragma unroll
      for (int kk = 0; kk < 2; ++kk) {
        bf16x8 af[4], bfr[4];
#pragma unroll
        for (int mt = 0; mt < 4; ++mt) {
          int row = wm * 64 + mt * 16 + l15;
          af[mt] = *(const bf16x8*)&Albuf[row * 64 + (((kk * 4 + lg) ^ (row & 7))) * 8];
        }
#pragma unroll
        for (int nt = 0; nt < 4; ++nt) {
          int p = wn * 64 + nt * 16 + l15;
          int r = (p >> 6) + dh;
          int col = ((p & 63) + dw) & 63;
          bfr[nt] = *(const bf16x8*)&slab[((r * 64 + col) * 8 + ((kk * 4 + lg) ^ (col & 7))) * 8];
        }
#pragma unroll
        for (int mt = 0; mt < 4; ++mt)
#pragma unroll
          for (int nt = 0; nt < 4; ++nt)
            acc[mt][nt] = __builtin_amdgcn_mfma_f32_16x16x32_bf16(af[mt], bfr[nt], acc[mt][nt], 0, 0, 0);
      }
      __syncthreads();             // everyone done reading Albuf (and slab at tap 8)
      if (haveNext) {
        writeA(ra);                // next A tile into the single buffer
        if (tap == 8) stage_slab(cc + 1);
        __syncthreads();           // ds_writes + slab gloads visible
      }
    }
  }

  // fused SE2 + sigmoid (LDS overlay on dead slab area)
  if (t < 144) w2s[t] = se_w2[t];
  __syncthreads();
  if (t < 112) {
    int r = t / 56, w = t - r * 56;
    int h = h0 + r;
    float s = 0.f;
    for (int dh2 = 0; dh2 < 3; ++dh2) {
#pragma unroll
      for (int dw2 = 0; dw2 < 3; ++dw2) {
        const u16* src = se1p + ((size_t)((b * HP + h + dh2) * HP + (w + dw2))) * 16;
        us8 v0 = *(const us8*)src;
        us8 v1 = *(const us8*)(src + 8);
        int tap = dh2 * 3 + dw2;
#pragma unroll
        for (int ci = 0; ci < 8; ++ci) s += bf2f(v0[ci]) * w2s[ci * 9 + tap];
#pragma unroll
        for (int ci = 0; ci < 8; ++ci) s += bf2f(v1[ci]) * w2s[(8 + ci) * 9 + tap];
      }
    }
    amap_s[t] = 1.f / (1.f + expf(-s));
  }
  __syncthreads();
  // epilogue: multiply by attention map, store NCHW fp32
#pragma unroll
  for (int nt = 0; nt < 4; ++nt) {
    int n = wn * 64 + nt * 16 + l15;
    int r = n >> 6, w = n & 63;
    if (w < 56) {
      float av = amap_s[r * 56 + w];
#pragma unroll
      for (int mt = 0; mt < 4; ++mt) {
        int obase = mbase + wm * 64 + mt * 16 + lg * 4;
#pragma unroll
        for (int reg = 0; reg < 4; ++reg) {
          out[((size_t)(b * 256 + obase + reg) * 56 + h0 + r) * 56 + w] = acc[mt][nt][reg] * av;
        }
      }
    }
  }
}

extern "C" void kernel_launch(void* const* d_in, const int* in_sizes, int n_in,
                              void* d_out, int out_size, void* d_ws, size_t ws_size,
                              hipStream_t stream) {
  const float* x      = (const float*)d_in[0];
  const float* weight = (const float*)d_in[1];
  const float* A_w    = (const float*)d_in[2];
  const float* se_w1  = (const float*)d_in[3];
  const float* se_w2  = (const float*)d_in[4];
  float* out = (float*)d_out;

  char* ws = (char*)d_ws;
  u16* xp   = (u16*)ws;                    // [8][58][58][256] bf16
  u16* se1p = (u16*)(ws + 13778944);       // [8][58][58][16]  bf16
  u16* wb   = (u16*)(ws + 14640128);       // [9][256][256]    bf16
  u16* w1b  = (u16*)(ws + 15819776);       // [9][16][256]     bf16

  k_pre<<<dim3(3072), dim3(256), 0, stream>>>(x, weight, A_w, se_w1, xp, wb, w1b, se1p);
  k_se1<<<dim3(448), dim3(256), 0, stream>>>(xp, w1b, se1p);
  k_main<<<dim3(448), dim3(256), 0, stream>>>(xp, wb, se1p, se_w2, out);
}

// Round 9
// 150.238 us; speedup vs baseline: 1.1407x; 1.0668x over previous
//
#include <hip/hip_runtime.h>

// ALayer: out = conv3x3(x, weight*A_w) * sigmoid(conv3x3(relu(conv3x3(x,se_w1)), se_w2))
// B=8, C=256, H=W=56. bf16 MFMA implicit GEMM on NHWC-padded input.
// Round 6 (3rd resubmit after infra timeouts): k_main = 512 thr / 8 waves, BM=128
// BN=128, slab(32K) + A-dbuf(2x16K) = 64KB exact -> 2 blocks/CU; counted vmcnt(2)
// schedule, setprio around MFMA; overlay epilogue arrays. k_pre weight-prep coalesced.

typedef unsigned short u16;
typedef __bf16 bf16x8 __attribute__((ext_vector_type(8)));
typedef unsigned short us8 __attribute__((ext_vector_type(8)));
typedef unsigned short us4v __attribute__((ext_vector_type(4)));
typedef float f32x4 __attribute__((ext_vector_type(4)));
typedef float f4v __attribute__((ext_vector_type(4)));

#define HP 58   // padded H/W
#define HW 3136 // 56*56

__device__ __forceinline__ u16 f2bf(float f) {
  unsigned u = __float_as_uint(f);
  u = (u + 0x7fffu + ((u >> 16) & 1u)) >> 16;  // RNE, inputs finite
  return (u16)u;
}
__device__ __forceinline__ float bf2f(u16 v) {
  return __uint_as_float(((unsigned)v) << 16);
}

// async global->LDS, 16B per lane. LDS dest is wave-uniform base + lane*16.
__device__ __forceinline__ void gload16(const u16* g, u16* l) {
  __builtin_amdgcn_global_load_lds((const __attribute__((address_space(1))) void*)g,
                                   (__attribute__((address_space(3))) void*)l,
                                   16, 0, 0);
}

// ---------- k_pre: fused transform (NCHW f32 -> padded NHWC bf16) + weight prep
// + border zeroing. Grid 896.
// blocks [0,448): transform row (h=bid%56, b=bid/56) + zero border cols
// blocks [448,704): wb prep, one (o,c) per thread (contiguous 36B reads)
// blocks [704,720): w1b prep
// blocks [720,896): zero xp rows 0,57 + all of se1p
__global__ __launch_bounds__(256) void k_pre(const float* __restrict__ x,
                                             const float* __restrict__ weight,
                                             const float* __restrict__ A_w,
                                             const float* __restrict__ se_w1,
                                             u16* __restrict__ xp, u16* __restrict__ wb,
                                             u16* __restrict__ w1b, u16* __restrict__ se1p) {
  __shared__ __align__(16) u16 trans[56 * 72];
  const int bid = blockIdx.x;
  const int t = threadIdx.x;
  if (bid < 448) {
    const int h = bid % 56, b = bid / 56;
    if (t < 64) {
      int half = t >> 5, seg = t & 31;
      us8 z8 = {};
      *(us8*)(xp + ((size_t)((b * HP + h + 1) * HP + half * 57)) * 256 + seg * 8) = z8;
    }
    for (int cc = 0; cc < 4; ++cc) {
      const int c0 = cc * 64;
#pragma unroll
      for (int i = 0; i < 4; ++i) {
        int idx = t + 256 * i;
        if (idx < 896) {
          int ci = idx / 14, s = idx % 14;
          f4v v = *(const f4v*)(x + ((size_t)(b * 256 + c0 + ci)) * HW + h * 56 + s * 4);
#pragma unroll
          for (int j = 0; j < 4; ++j) trans[(s * 4 + j) * 72 + ci] = f2bf(v[j]);
        }
      }
      __syncthreads();
#pragma unroll
      for (int i = 0; i < 2; ++i) {
        int idx = t + 256 * i;
        if (idx < 448) {
          int w = idx >> 3, seg = idx & 7;
          us8 v = *(const us8*)&trans[w * 72 + seg * 8];
          *(us8*)(xp + ((size_t)((b * HP + h + 1) * HP + (w + 1))) * 256 + c0 + seg * 8) = v;
        }
      }
      __syncthreads();
    }
  } else if (bid < 704) {
    int idx = (bid - 448) * 256 + t;  // (o,c) pair
    int o = idx >> 8, c = idx & 255;
    const float* wsrc = weight + (size_t)idx * 9;
    const float* asrc = A_w + c * 9;
#pragma unroll
    for (int tap = 0; tap < 9; ++tap)
      wb[tap * 65536 + o * 256 + c] = f2bf(wsrc[tap] * asrc[tap]);
  } else if (bid < 720) {
    int idx = (bid - 704) * 256 + t;  // (o,c), o<16
    if (idx < 4096) {
      const float* wsrc = se_w1 + (size_t)idx * 9;
#pragma unroll
      for (int tap = 0; tap < 9; ++tap)
        w1b[tap * 4096 + idx] = f2bf(wsrc[tap]);
    }
  } else {
    int zid = (bid - 720) * 256 + t;  // 0..45055
    us8 z8 = {};
#pragma unroll
    for (int j = 0; j < 2; ++j) {
      int ch = zid + j * 45056;
      if (ch < 29696) {  // xp rows 0 and 57, all b
        int b = ch / 3712; int rem = ch - b * 3712;
        int row = (rem < 1856) ? 0 : 57;
        int r2 = (rem < 1856) ? rem : rem - 1856;
        int col = r2 >> 5, seg = r2 & 31;
        *(us8*)(xp + ((size_t)((b * HP + row) * HP + col)) * 256 + seg * 8) = z8;
      } else if (ch < 29696 + 53824) {  // all of se1p
        int c2 = ch - 29696;
        *(us8*)(se1p + (size_t)c2 * 8) = z8;
      }
    }
  }
}

// ---------- SE conv1 + relu: one output row per block (448 blocks), M=16, N=64.
__global__ __launch_bounds__(256) void k_se1(const u16* __restrict__ xp,
                                             const u16* __restrict__ w1b,
                                             u16* __restrict__ se1p) {
  __shared__ __align__(16) u16 Alds[144 * 64];      // 18432 B, swizzled [row][slot]
  __shared__ __align__(16) u16 slab[3 * 64 * 64];   // 24576 B
  const int t = threadIdx.x;
  const int lane = t & 63;
  const int wv = t >> 6;
  const int l15 = lane & 15, lg = lane >> 4;
  const int wg = blockIdx.x;      // 448: b = XCD
  const int b = wg & 7;
  const int h = wg >> 3;          // output row 0..55

  f32x4 acc = {0.f, 0.f, 0.f, 0.f};

  for (int cc = 0; cc < 4; ++cc) {
    const int c0 = cc * 64;
    __syncthreads();
    for (int idx = t; idx < 1152; idx += 256) {
      int row = idx >> 3, seg = idx & 7;
      us8 v = *(const us8*)(w1b + ((size_t)(row / 16) * 4096 + (row & 15) * 256 + c0 + seg * 8));
      *(us8*)&Alds[row * 64 + (seg ^ (row & 7)) * 8] = v;
    }
#pragma unroll
    for (int i = 0; i < 6; ++i) {
      int chunk = i * 256 + t;
      int row = chunk >> 9, col = (chunk >> 3) & 63, seg = chunk & 7;
      const u16* src = xp + ((size_t)((b * HP + h + row) * HP + col)) * 256 + c0 +
                       ((seg ^ (col & 7)) * 8);
      gload16(src, &slab[(i * 256 + wv * 64) * 8]);
    }
    __syncthreads();
#pragma unroll
    for (int tap = 0; tap < 9; ++tap) {
      const int dh = tap / 3, dw = tap % 3;
#pragma unroll
      for (int kk = 0; kk < 2; ++kk) {
        int arow = tap * 16 + l15;
        bf16x8 af = *(const bf16x8*)&Alds[arow * 64 + (((kk * 4 + lg) ^ (arow & 7))) * 8];
        int col = ((wv * 16 + l15) + dw) & 63;
        bf16x8 bfr = *(const bf16x8*)&slab[((dh * 64 + col) * 8 + ((kk * 4 + lg) ^ (col & 7))) * 8];
        acc = __builtin_amdgcn_mfma_f32_16x16x32_bf16(af, bfr, acc, 0, 0, 0);
      }
    }
  }
  int w = wv * 16 + l15;
  if (w < 56) {
    us4v pk;
#pragma unroll
    for (int reg = 0; reg < 4; ++reg) {
      float v = acc[reg];
      v = v > 0.f ? v : 0.f;
      pk[reg] = f2bf(v);
    }
    *(us4v*)(se1p + ((size_t)((b * HP + h + 1) * HP + (w + 1))) * 16 + lg * 4) = pk;
  }
}

// ---------- main conv: BM=128, BN=128 (2 rows x 64), 8 waves (2M x 4N), LDS 64KB.
// slab resident per cc (9 taps read shifted); A double-buffered via gload_lds
// with counted vmcnt(2). Fused SE2+sigmoid epilogue (overlay).
__global__ __launch_bounds__(512, 4) void k_main(const u16* __restrict__ xp,
                                                 const u16* __restrict__ wb,
                                                 const u16* __restrict__ se1p,
                                                 const float* __restrict__ se_w2,
                                                 float* __restrict__ out) {
  __shared__ __align__(16) u16 S[32768];  // 65536 B total
  u16* slab = S;                 // 16384 u16 = 32KB : [4 rows][64 cols][8 slots][8]
  u16* Albuf0 = S + 16384;       // 2 x 8KB halves: [128 rows][8 slots][8]
  float* w2s    = (float*)S;          // epilogue overlay (slab dead by then)
  float* amap_s = (float*)(S + 512);  // byte offset 1024
  const int t = threadIdx.x;
  const int lane = t & 63;
  const int wid = t >> 6;           // 0..7
  const int wm = wid >> 2;          // 0..1 : 64 out-channels
  const int wn = wid & 3;           // 0..3 : 32 pixels
  const int l15 = lane & 15, lg = lane >> 4;
  const int lrow = lane >> 3, lseg = lane & 7;
  // XCD swizzle: 448 blocks, 56 per XCD -> each XCD owns one batch b
  const int wg = blockIdx.x;
  const int b = wg & 7;
  const int rem = wg >> 3;          // 0..55
  const int h0 = (rem >> 1) * 2;
  const int mbase = (rem & 1) * 128;

  f32x4 acc[4][2];
#pragma unroll
  for (int mt = 0; mt < 4; ++mt)
#pragma unroll
    for (int nt = 0; nt < 2; ++nt) {
      f32x4 z = {0.f, 0.f, 0.f, 0.f};
      acc[mt][nt] = z;
    }

  auto stage_slab = [&](int cc) {
    const int c0 = cc * 64;
#pragma unroll
    for (int i = 0; i < 4; ++i) {
      int chunk = wid * 256 + i * 64 + lane;
      int row = chunk >> 9, col = (chunk >> 3) & 63, seg = chunk & 7;
      const u16* src = xp + ((size_t)((b * HP + h0 + row) * HP + col)) * 256 + c0 +
                       ((seg ^ (col & 7)) * 8);
      gload16(src, &slab[(wid * 256 + i * 64) * 8]);
    }
  };
  auto stage_A = [&](int tap, int cc, int buf) {
    const int c0 = cc * 64;
    u16* dst = Albuf0 + buf * 8192;
#pragma unroll
    for (int i = 0; i < 2; ++i) {
      int li = wid * 2 + i;          // 0..15
      int row = li * 8 + lrow;       // 0..127
      const u16* src = wb + ((size_t)(tap * 256 + mbase + row)) * 256 + c0 +
                       ((lseg ^ (row & 7)) * 8);
      gload16(src, &dst[li * 512]);
    }
  };

  stage_slab(0);
  stage_A(0, 0, 0);   // 6 loads/thread outstanding
  int pb = 0;
  for (int cc = 0; cc < 4; ++cc) {
#pragma unroll
    for (int tap = 0; tap < 9; ++tap) {
      if (tap < 8) {
        stage_A(tap + 1, cc, pb ^ 1);
        asm volatile("s_waitcnt vmcnt(2)" ::: "memory");  // this tap's data landed
      } else {
        asm volatile("s_waitcnt vmcnt(0)" ::: "memory");
      }
      __builtin_amdgcn_s_barrier();
      __builtin_amdgcn_sched_barrier(0);
      const int dh = tap / 3, dw = tap % 3;
      const u16* Ab = Albuf0 + pb * 8192;
      __builtin_amdgcn_s_setprio(1);
#pragma unroll
      for (int kk = 0; kk < 2; ++kk) {
        bf16x8 af[4], bfr[2];
#pragma unroll
        for (int mt = 0; mt < 4; ++mt) {
          int row = wm * 64 + mt * 16 + l15;
          af[mt] = *(const bf16x8*)&Ab[row * 64 + (((kk * 4 + lg) ^ (row & 7))) * 8];
        }
#pragma unroll
        for (int nt = 0; nt < 2; ++nt) {
          int p = wn * 32 + nt * 16 + l15;
          int r = (p >> 6) + dh;
          int col = ((p & 63) + dw) & 63;
          bfr[nt] = *(const bf16x8*)&slab[((r * 64 + col) * 8 + ((kk * 4 + lg) ^ (col & 7))) * 8];
        }
#pragma unroll
        for (int mt = 0; mt < 4; ++mt)
#pragma unroll
          for (int nt = 0; nt < 2; ++nt)
            acc[mt][nt] = __builtin_amdgcn_mfma_f32_16x16x32_bf16(af[mt], bfr[nt], acc[mt][nt], 0, 0, 0);
      }
      __builtin_amdgcn_s_setprio(0);
      __builtin_amdgcn_sched_barrier(0);  // all LDS reads before end barrier
      __builtin_amdgcn_s_barrier();
      if (tap == 8 && cc < 3) {
        stage_slab(cc + 1);            // safe: everyone passed the read barrier
        stage_A(0, cc + 1, pb ^ 1);    // 6 outstanding into next phase
      }
      pb ^= 1;
    }
  }

  // fused SE2 + sigmoid (LDS overlay on dead slab area)
  if (t < 144) w2s[t] = se_w2[t];
  __syncthreads();
  if (t < 112) {
    int r = t / 56, w = t - r * 56;
    int h = h0 + r;
    float s = 0.f;
    for (int dh2 = 0; dh2 < 3; ++dh2) {
#pragma unroll
      for (int dw2 = 0; dw2 < 3; ++dw2) {
        const u16* src = se1p + ((size_t)((b * HP + h + dh2) * HP + (w + dw2))) * 16;
        us8 v0 = *(const us8*)src;
        us8 v1 = *(const us8*)(src + 8);
        int tap = dh2 * 3 + dw2;
#pragma unroll
        for (int ci = 0; ci < 8; ++ci) s += bf2f(v0[ci]) * w2s[ci * 9 + tap];
#pragma unroll
        for (int ci = 0; ci < 8; ++ci) s += bf2f(v1[ci]) * w2s[(8 + ci) * 9 + tap];
      }
    }
    amap_s[t] = 1.f / (1.f + expf(-s));
  }
  __syncthreads();
  // epilogue: multiply by attention map, store NCHW fp32
#pragma unroll
  for (int nt = 0; nt < 2; ++nt) {
    int n = wn * 32 + nt * 16 + l15;
    int r = n >> 6, w = n & 63;
    if (w < 56) {
      float av = amap_s[r * 56 + w];
#pragma unroll
      for (int mt = 0; mt < 4; ++mt) {
        int obase = mbase + wm * 64 + mt * 16 + lg * 4;
#pragma unroll
        for (int reg = 0; reg < 4; ++reg) {
          out[((size_t)(b * 256 + obase + reg) * 56 + h0 + r) * 56 + w] = acc[mt][nt][reg] * av;
        }
      }
    }
  }
}

extern "C" void kernel_launch(void* const* d_in, const int* in_sizes, int n_in,
                              void* d_out, int out_size, void* d_ws, size_t ws_size,
                              hipStream_t stream) {
  const float* x      = (const float*)d_in[0];
  const float* weight = (const float*)d_in[1];
  const float* A_w    = (const float*)d_in[2];
  const float* se_w1  = (const float*)d_in[3];
  const float* se_w2  = (const float*)d_in[4];
  float* out = (float*)d_out;

  char* ws = (char*)d_ws;
  u16* xp   = (u16*)ws;                    // [8][58][58][256] bf16
  u16* se1p = (u16*)(ws + 13778944);       // [8][58][58][16]  bf16
  u16* wb   = (u16*)(ws + 14640128);       // [9][256][256]    bf16
  u16* w1b  = (u16*)(ws + 15819776);       // [9][16][256]     bf16

  k_pre<<<dim3(896), dim3(256), 0, stream>>>(x, weight, A_w, se_w1, xp, wb, w1b, se1p);
  k_se1<<<dim3(448), dim3(256), 0, stream>>>(xp, w1b, se1p);
  k_main<<<dim3(448), dim3(512), 0, stream>>>(xp, wb, se1p, se_w2, out);
}